// Round 11
// baseline (265.582 us; speedup 1.0000x reference)
//
#include <hip/hip_runtime.h>

#define B_   32
#define L_   1024
#define CD_  256
#define ZD_  256
#define P_   12
#define NEG_ 8
#define TL_  32    // l-rows per block

typedef __attribute__((ext_vector_type(8))) short bf16x8;
typedef __attribute__((ext_vector_type(4))) float f32x4;
typedef __attribute__((ext_vector_type(4))) int   i32x4;

// LDS map (dynamic): [0,131072) z-windows (8 x 32 rows x 512B bf16, row-XOR swz)
//                    [131072,147456) Wc (32 rows x 512B bf16, row-XOR swz)
//                    [147456,148224) pbuf: pbm[3][32], pbs[3][32]
#define LDS_TOTAL 148480
#define WC_OFF    131072
#define PB_OFF    147456

#define SCC  (127.0f / 4.2f)                      // c int8 quant scale
#define FDQ  ((1.0f / 127.0f) * (4.2f / 127.0f)) // dequant for acc

__device__ __forceinline__ unsigned short f2b(float f) {
    unsigned u = __float_as_uint(f);
    u += 0x7FFFu + ((u >> 16) & 1u);              // round-nearest-even
    return (unsigned short)(u >> 16);
}

__device__ __forceinline__ void glds16(const void* g, void* l) {
    __builtin_amdgcn_global_load_lds(
        (const __attribute__((address_space(1))) unsigned int*)g,
        (__attribute__((address_space(3))) unsigned int*)l, 16, 0, 0);
}

// ws: ws[0]=loss, ws[1]=msum; Wi8 @byte 256: frag-major [p][kk4][hi][d][16B] i8
// prep: blk<192: W->Wi8 quant+transpose; blk 192: init
__global__ __launch_bounds__(256) void cnce_prep(
        const float* __restrict__ W, signed char* __restrict__ Wi8,
        const int* __restrict__ length, float* __restrict__ ws) {
    const int blk = blockIdx.x;
    const int tid = threadIdx.x;
    if (blk < 192) {
        const int p = blk >> 4, kk4 = (blk >> 2) & 3, hig = blk & 3;
        unsigned wds[4];
        #pragma unroll
        for (int qq = 0; qq < 4; ++qq) {
            unsigned u = 0;
            #pragma unroll
            for (int e = 0; e < 4; ++e) {
                int cc = kk4 * 64 + hig * 16 + qq * 4 + e;
                int q = (int)(W[((size_t)p * CD_ + cc) * ZD_ + tid] * 127.f + 0.5f);
                u |= ((unsigned)(q & 255)) << (8 * e);
            }
            wds[qq] = u;
        }
        *(int4*)(Wi8 + ((size_t)blk * 256 + tid) * 16) = *(const int4*)wds;
    } else {
        if (tid < 64) {
            int v = (tid < B_) ? length[tid] : 0;
            #pragma unroll
            for (int mm = 1; mm < 64; mm <<= 1) v += __shfl_xor(v, mm);
            if (tid == 0) { ws[0] = 0.f; ws[1] = (float)v; }
        }
    }
}

__global__ __launch_bounds__(512, 2) void cnce_main(
        const float* __restrict__ c, const float* __restrict__ z,
        const signed char* __restrict__ Wi8,
        const int* __restrict__ neg_shift,
        const int* __restrict__ length, float* __restrict__ ws) {
    extern __shared__ char smem[];
    char* zw  = smem;
    char* wcb = smem + WC_OFF;
    float* pbm = (float*)(smem + PB_OFF);
    float* pbs = pbm + 96;

    // XCD swizzle: 1024 blocks = 8 XCD x 128; XCD k gets b in [4k,4k+4)
    const int hbx  = blockIdx.x;
    const int work = ((hbx & 7) << 7) | (hbx >> 3);
    const int b  = work >> 5;
    const int l0 = (work & 31) * TL_;
    const int tid  = threadIdx.x;
    const int w    = tid >> 6;          // 0..7
    const int lane = tid & 63;
    const int hi   = lane >> 4;
    const int m    = lane & 15;
    const int rg   = w & 1;             // row-group: rows rg*16+m
    const int jg   = w >> 1;            // j-subset: 0:{pos,n0,n1} 1:{n2,n3} 2:{n4,n5} 3:{n6,n7}

    int sh8[NEG_];
    #pragma unroll
    for (int j = 0; j < NEG_; ++j) sh8[j] = neg_shift[j];
    const int len_b = length[b];
    const bool owner = (hi == (m >> 2));
    const int  rsel  = m & 3;
    const int  l     = rg * 16 + m;     // phase-B row within tile
    const int  gl    = l0 + l;

    // ---- stage c f32 into zw[0..32768) (linear dest, src col pre-XOR'd) ----
    {
        const char* cb = (const char*)(c + (size_t)(b * L_ + l0) * CD_);
        #pragma unroll
        for (int i = 0; i < 4; ++i) {
            int f = i * 8192 + w * 1024 + (lane << 4);
            int row = f >> 10, col = f & 1023;
            glds16(cb + ((size_t)row << 10) + (col ^ ((row & 7) << 4)),
                   zw + i * 8192 + w * 1024);
        }
    }
    __syncthreads();

    // ---- c fragments -> int8 (MFMA B-operand), registers ----
    i32x4 cf[4][2];
    #pragma unroll
    for (int kk4 = 0; kk4 < 4; ++kk4)
        #pragma unroll
        for (int ni = 0; ni < 2; ++ni) {
            int lr = ni * 16 + m;
            int cb0 = kk4 * 256 + hi * 64;          // f32 byte offset in 1024B row
            unsigned wd[4];
            #pragma unroll
            for (int qq = 0; qq < 4; ++qq) {
                float4 v = *(const float4*)(zw + lr * 1024 + ((cb0 + qq * 16) ^ ((lr & 7) << 4)));
                int q0 = (int)rintf(fminf(fmaxf(v.x * SCC, -127.f), 127.f));
                int q1 = (int)rintf(fminf(fmaxf(v.y * SCC, -127.f), 127.f));
                int q2 = (int)rintf(fminf(fmaxf(v.z * SCC, -127.f), 127.f));
                int q3 = (int)rintf(fminf(fmaxf(v.w * SCC, -127.f), 127.f));
                wd[qq] = (q0 & 255) | ((q1 & 255) << 8) | ((q2 & 255) << 16) | ((q3 & 255) << 24);
            }
            cf[kk4][ni] = *(const i32x4*)wd;
        }
    __syncthreads();   // done reading c region; zwin may overwrite

    // ---- stage 8 negative z-windows (f32 -> bf16, row-XOR swizzled) ----
    #pragma unroll
    for (int i = 0; i < 16; ++i) {
        int f = i * 8192 + tid * 16;
        int win = f >> 14, r = (f >> 9) & 31, colB = f & 511;
        int zrow = (l0 + sh8[win] + r) & (L_ - 1);
        const float* zp = z + (size_t)(b * L_ + zrow) * ZD_ + (colB >> 1);
        float4 a = *(const float4*)zp, b4 = *(const float4*)(zp + 4);
        unsigned short hh[8] = { f2b(a.x), f2b(a.y), f2b(a.z), f2b(a.w),
                                 f2b(b4.x), f2b(b4.y), f2b(b4.z), f2b(b4.w) };
        *(int4*)(zw + (win << 14) + r * 512 + (colB ^ ((r & 7) << 4))) = *(const int4*)hh;
    }

    const float* zbF = z + (size_t)b * L_ * ZD_;

    i32x4 acc[2][2];
    auto do_gemm = [&](int p) {
        #pragma unroll
        for (int mi = 0; mi < 2; ++mi)
            #pragma unroll
            for (int ni = 0; ni < 2; ++ni) acc[mi][ni] = (i32x4){0, 0, 0, 0};
        const signed char* wp = Wi8 + (size_t)p * 65536;
        #pragma unroll
        for (int kk4 = 0; kk4 < 4; ++kk4) {
            const signed char* sl = wp + (kk4 * 4 + hi) * 4096;
            i32x4 wf0 = *(const i32x4*)(sl + (w * 32 + m) * 16);
            i32x4 wf1 = *(const i32x4*)(sl + (w * 32 + 16 + m) * 16);
            acc[0][0] = __builtin_amdgcn_mfma_i32_16x16x64_i8(wf0, cf[kk4][0], acc[0][0], 0, 0, 0);
            acc[0][1] = __builtin_amdgcn_mfma_i32_16x16x64_i8(wf0, cf[kk4][1], acc[0][1], 0, 0, 0);
            acc[1][0] = __builtin_amdgcn_mfma_i32_16x16x64_i8(wf1, cf[kk4][0], acc[1][0], 0, 0, 0);
            acc[1][1] = __builtin_amdgcn_mfma_i32_16x16x64_i8(wf1, cf[kk4][1], acc[1][1], 0, 0, 0);
        }
    };
    auto do_spill = [&]() {
        #pragma unroll
        for (int mi = 0; mi < 2; ++mi)
            #pragma unroll
            for (int ni = 0; ni < 2; ++ni) {
                int lr = ni * 16 + m;
                int d0 = w * 32 + mi * 16 + hi * 4;
                unsigned short hh[4] = { f2b((float)acc[mi][ni][0] * FDQ),
                                         f2b((float)acc[mi][ni][1] * FDQ),
                                         f2b((float)acc[mi][ni][2] * FDQ),
                                         f2b((float)acc[mi][ni][3] * FDQ) };
                *(uint2*)(wcb + ((lr * 512 + d0 * 2) ^ ((lr & 15) << 4))) = *(const uint2*)hh;
            }
    };

    float lsum = 0.f;
    do_gemm(0);
    __syncthreads();   // zwin writes visible; safe to spill
    do_spill();
    __syncthreads();

    for (int p = 0; p < P_; ++p) {
        if (p < P_ - 1) do_gemm(p + 1);      // overlaps with phase-B below
        // ---- phase B(p) ----
        bf16x8 pav[8];
        #pragma unroll
        for (int kk = 0; kk < 8; ++kk)
            pav[kk] = *(const bf16x8*)(wcb + ((l * 512 + kk * 64 + hi * 16) ^ ((l & 15) << 4)));
        const int NJ = (jg == 0) ? 3 : 2;
        float sc[3];
        sc[2] = -3e38f;
        #pragma unroll
        for (int j2 = 0; j2 < 3; ++j2) {
            if (j2 >= NJ) continue;
            f32x4 e = {0.f, 0.f, 0.f, 0.f}, o = {0.f, 0.f, 0.f, 0.f};
            if (jg == 0 && j2 == 0) {
                // positive: rows from global f32 z, convert on the fly
                const int rowz = (gl + p + 1) & (L_ - 1);
                const float* zr = zbF + (size_t)rowz * ZD_ + hi * 8;
                #pragma unroll
                for (int kk = 0; kk < 8; ++kk) {
                    float4 z0 = *(const float4*)(zr + kk * 32);
                    float4 z1 = *(const float4*)(zr + kk * 32 + 4);
                    unsigned short hh[8] = { f2b(z0.x), f2b(z0.y), f2b(z0.z), f2b(z0.w),
                                             f2b(z1.x), f2b(z1.y), f2b(z1.z), f2b(z1.w) };
                    bf16x8 bz = *(const bf16x8*)hh;
                    if (kk & 1) o = __builtin_amdgcn_mfma_f32_16x16x32_bf16(pav[kk], bz, o, 0, 0, 0);
                    else        e = __builtin_amdgcn_mfma_f32_16x16x32_bf16(pav[kk], bz, e, 0, 0, 0);
                }
            } else {
                const int win = (jg == 0) ? (j2 - 1) : (2 * jg + j2);
                const char* base = zw + (win << 14) + l * 512;
                #pragma unroll
                for (int kk = 0; kk < 8; kk += 2) {
                    bf16x8 b0 = *(const bf16x8*)(base + ((kk * 64 + hi * 16)      ^ ((l & 7) << 4)));
                    bf16x8 b1 = *(const bf16x8*)(base + ((kk * 64 + 64 + hi * 16) ^ ((l & 7) << 4)));
                    e = __builtin_amdgcn_mfma_f32_16x16x32_bf16(pav[kk],     b0, e, 0, 0, 0);
                    o = __builtin_amdgcn_mfma_f32_16x16x32_bf16(pav[kk + 1], b1, o, 0, 0, 0);
                }
            }
            sc[j2] = (rsel == 0) ? e[0] + o[0] : (rsel == 1) ? e[1] + o[1]
                   : (rsel == 2) ? e[2] + o[2] : e[3] + o[3];
        }
        float mx = fmaxf(sc[0], sc[1]);
        if (NJ == 3) mx = fmaxf(mx, sc[2]);
        float se = __expf(sc[0] - mx) + __expf(sc[1] - mx);
        if (NJ == 3) se += __expf(sc[2] - mx);
        if (jg && owner) { pbm[(jg - 1) * 32 + l] = mx; pbs[(jg - 1) * 32 + l] = se; }
        __syncthreads();
        if (jg == 0) {
            float M = mx, S = se;
            #pragma unroll
            for (int q = 0; q < 3; ++q) {
                float pm = pbm[q * 32 + l], ps = pbs[q * 32 + l];
                float M2 = fmaxf(M, pm);
                S = S * __expf(M - M2) + ps * __expf(pm - M2);
                M = M2;
            }
            if (owner && gl < len_b) lsum += __logf(S) + M - sc[0];
        }
        if (p < P_ - 1) do_spill();
        __syncthreads();
    }

    if (jg == 0) {
        #pragma unroll
        for (int sh = 1; sh < 64; sh <<= 1) lsum += __shfl_xor(lsum, sh);
        if (lane == 0) atomicAdd(&ws[0], lsum);
    }
}

__global__ void cnce_fin(const float* __restrict__ ws, float* __restrict__ out) {
    out[0] = ws[0] / ws[1];
}

extern "C" void kernel_launch(void* const* d_in, const int* in_sizes, int n_in,
                              void* d_out, int out_size, void* d_ws, size_t ws_size,
                              hipStream_t stream) {
    const float* c  = (const float*)d_in[0];
    const float* z  = (const float*)d_in[1];
    const float* W  = (const float*)d_in[2];
    const int* neg_shift = (const int*)d_in[3];
    const int* length    = (const int*)d_in[4];
    float* out = (float*)d_out;
    float* ws  = (float*)d_ws;
    signed char* Wi8 = (signed char*)((char*)d_ws + 256);

    (void)hipFuncSetAttribute((const void*)cnce_main,
                              hipFuncAttributeMaxDynamicSharedMemorySize, LDS_TOTAL);

    cnce_prep<<<193, 256, 0, stream>>>(W, Wi8, length, ws);
    cnce_main<<<1024, 512, LDS_TOTAL, stream>>>(c, z, Wi8, neg_shift, length, ws);
    cnce_fin<<<1, 1, 0, stream>>>(ws, out);
}